// Round 23
// baseline (237.423 us; speedup 1.0000x reference)
//
#include <hip/hip_runtime.h>
#include <math.h>

#define N_NODES 10000
#define N_EDGES 80000
#define ET (N_EDGES + N_NODES)   // 90000 edges incl. self-loops
#define IN_FEAT 200
#define HID 400
#define NH1 8
#define F1 (NH1 * HID)           // 3200
#define OUT_FEAT 200
#define NEG_SLOPE 0.2f

#define M_PAD 10048              // 628 mtiles * 16
#define K1 224                   // per-head K pad (200 -> 224 = 7*32)
#define HSL (NH1 * K1)           // 1792 bf16 per node (LDS staging)
#define XH_K 416                 // per-head hidden K pad (400 -> 416 = 13*32)
#define C1P 448                  // gemm1 col pad (400 -> 448 = 28*16)
#define KALL (NH1 * XH_K)        // 3328
#define N2P2 256                 // gemm2 col pad
#define XHS 456                  // LDS xh row stride (ushorts)
#define NQ 2                     // head-quad partials

typedef __attribute__((ext_vector_type(8))) short short8_t;
typedef __attribute__((ext_vector_type(4))) float f32x4;

// ---------- helpers ----------

__device__ inline void edge_sd(const int* __restrict__ ei, int e, int& s, int& d) {
    if (e < N_EDGES) { s = ei[e]; d = ei[N_EDGES + e]; }
    else { s = e - N_EDGES; d = s; }
}

__device__ inline unsigned short f2bf(float x) {
    unsigned u = __float_as_uint(x);
    unsigned r = u + 0x7FFFu + ((u >> 16) & 1u);
    return (unsigned short)(r >> 16);
}

// NaN-safe online-softmax pair merge
__device__ inline void sm_merge(float& m, float& l, float m2, float l2) {
    float mn = fmaxf(m, m2);
    float t1 = (m  > -1e30f) ? l  * __expf(m  - mn) : 0.f;
    float t2 = (m2 > -1e30f) ? l2 * __expf(m2 - mn) : 0.f;
    m = mn; l = t1 + t2;
}

// ---------- merged pre-kernel: prep_w + count_k + pvec_k (independent work) ----------
#define W1N (NH1 * C1P * K1)     // 802816
#define W2N (N2P2 * KALL)        // 851968
#define PW_BLK ((W1N + W2N + 255) / 256)   // 6464
#define CNT_BLK ((ET + 255) / 256)         // 352
#define PV_BLK ((2 * NH1 * IN_FEAT + 255) / 256)  // 13
__global__ __launch_bounds__(256) void pre_k(const float* __restrict__ W1,
                                             const float* __restrict__ W2,
                                             const int* __restrict__ ei,
                                             const float* __restrict__ a_src,
                                             const float* __restrict__ a_dst,
                                             unsigned short* __restrict__ W1f,
                                             unsigned short* __restrict__ W2f,
                                             int* __restrict__ counts,
                                             float* __restrict__ p_src,
                                             float* __restrict__ p_dst) {
    const int bid = blockIdx.x;
    if (bid < PW_BLK) {
        int idx = bid * 256 + threadIdx.x;
        if (idx < W1N) {
            int e    = idx & 7;
            int lane = (idx >> 3) & 63;
            int rem  = idx >> 9;
            int ks   = rem % 7;
            int jgh  = rem / 7;
            int jg   = jgh % 28;
            int h    = jgh / 28;
            int c = jg * 16 + (lane & 15);
            int k = ks * 32 + (lane >> 4) * 8 + e;
            float v = (k < IN_FEAT && c < HID) ? W1[(size_t)k * F1 + h * HID + c] : 0.f;
            W1f[idx] = f2bf(v);
        } else if (idx < W1N + W2N) {
            int t    = idx - W1N;
            int e    = t & 7;
            int lane = (t >> 3) & 63;
            int rem  = t >> 9;
            int ks   = rem % 13;
            int cgh  = rem / 13;
            int cg   = cgh % 16;
            int h    = cgh / 16;
            int c = cg * 16 + (lane & 15);
            int k = ks * 32 + (lane >> 4) * 8 + e;
            float v = (c < OUT_FEAT && k < HID) ? W2[(size_t)(h * HID + k) * OUT_FEAT + c] : 0.f;
            W2f[t] = f2bf(v);
        }
    } else if (bid < PW_BLK + CNT_BLK) {
        int e = (bid - PW_BLK) * 256 + threadIdx.x;
        if (e < ET) {
            int s, d; edge_sd(ei, e, s, d);
            atomicAdd(&counts[d], 1);
        }
    } else {
        int idx = (bid - PW_BLK - CNT_BLK) * 256 + threadIdx.x;
        if (idx < 2 * NH1 * IN_FEAT) {
            int which = idx / (NH1 * IN_FEAT);
            int r = idx - which * (NH1 * IN_FEAT);
            int h = r / IN_FEAT, k = r - h * IN_FEAT;
            const float* av = (which == 0 ? a_src : a_dst) + h * HID;
            const float* wrow = W1 + (size_t)k * F1 + h * HID;
            float acc = 0.f;
            for (int c = 0; c < HID; ++c) acc += wrow[c] * av[c];
            (which == 0 ? p_src : p_dst)[h * IN_FEAT + k] = acc;
        }
    }
}

// ---------- scan ----------
__global__ __launch_bounds__(1024) void scan_k(const int* __restrict__ counts, int* __restrict__ offs) {
    __shared__ int part[1024];
    const int tid = threadIdx.x;
    const int base = tid * 10;
    int loc[10];
    int s = 0;
    for (int i = 0; i < 10; ++i) {
        int idx = base + i;
        int c = (idx < N_NODES) ? counts[idx] : 0;
        loc[i] = s; s += c;
    }
    part[tid] = s;
    __syncthreads();
    for (int off = 1; off < 1024; off <<= 1) {
        int v = (tid >= off) ? part[tid - off] : 0;
        __syncthreads();
        part[tid] += v;
        __syncthreads();
    }
    int pre = (tid > 0) ? part[tid - 1] : 0;
    for (int i = 0; i < 10; ++i) {
        int idx = base + i;
        if (idx < N_NODES) offs[idx] = pre + loc[i];
    }
    if (tid == 1023) offs[N_NODES] = part[1023];
}

// ---------- merged mid-kernel: scatter_k + att1x ----------
#define SC_BLK ((ET + 511) / 512)   // 176
__global__ __launch_bounds__(512) void mid_k(const int* __restrict__ ei,
                                             const int* __restrict__ offs,
                                             int* __restrict__ cursor,
                                             int* __restrict__ esrc,
                                             const float* __restrict__ X,
                                             const float* __restrict__ p_src,
                                             const float* __restrict__ p_dst,
                                             float* __restrict__ als,
                                             float* __restrict__ ald) {
    const int bid = blockIdx.x;
    if (bid < SC_BLK) {
        int e = bid * 512 + threadIdx.x;
        if (e < ET) {
            int s, d; edge_sd(ei, e, s, d);
            int pos = atomicAdd(&cursor[d], 1);
            esrc[offs[d] + pos] = s;
        }
    } else {
        const int n    = bid - SC_BLK;
        const int head = threadIdx.x >> 6;
        const int lane = threadIdx.x & 63;
        const float* xp = X + (size_t)n * IN_FEAT;
        const float* ps = p_src + head * IN_FEAT;
        const float* pd = p_dst + head * IN_FEAT;
        float ss = 0.f, sd = 0.f;
        for (int k = lane; k < IN_FEAT; k += 64) {
            float v = xp[k];
            ss += v * ps[k];
            sd += v * pd[k];
        }
        for (int off = 32; off; off >>= 1) {
            ss += __shfl_down(ss, off);
            sd += __shfl_down(sd, off);
        }
        if (lane == 0) { als[n * NH1 + head] = ss; ald[n * NH1 + head] = sd; }
    }
}

// ---------- Stage A: parallel online softmax + aggregation -> FRAGMENT-MAJOR xaggb ----------
// xaggb layout: ((mtile*8 + h)*7 + ks)*512 + (kg*16 + row)*8 + e
//   where node = mtile*16 + row, k = ks*32 + kg*8 + e
__global__ __launch_bounds__(512) void agg1x(const float* __restrict__ X,
                                             const float* __restrict__ als1,
                                             const float* __restrict__ ald1,
                                             const int* __restrict__ offs,
                                             const int* __restrict__ esrc,
                                             unsigned short* __restrict__ xaggb) {
    __shared__ unsigned short sb[8][HSL];   // 28672 B, [node][h*224 + k]
    const int wave = threadIdx.x >> 6;
    const int lane = threadIdx.x & 63;
    const int n = blockIdx.x * 8 + wave;

    if (n < N_NODES) {
        float acc[NH1][4];
#pragma unroll
        for (int h = 0; h < NH1; ++h)
#pragma unroll
            for (int g = 0; g < 4; ++g) acc[h][g] = 0.f;

        const int beg = offs[n], end = offs[n + 1];
        const int grp = lane >> 3;    // edge group 0..7
        const int hd  = lane & 7;     // head
        const float aldv = ald1[n * NH1 + hd];

        // pass 1: all 64 lanes — 8 edge-groups x 8 heads, shfl-merged
        float m = -INFINITY, l = 0.f;
        for (int t = beg + grp; t < end; t += 8) {
            const int s = esrc[t];
            float v = als1[s * NH1 + hd] + aldv;
            v = v > 0.f ? v : NEG_SLOPE * v;
            float mn = fmaxf(m, v);
            l = l * __expf(m - mn) + __expf(v - mn);
            m = mn;
        }
#pragma unroll
        for (int off = 8; off < 64; off <<= 1) {
            float m2 = __shfl_xor(m, off);
            float l2 = __shfl_xor(l, off);
            sm_merge(m, l, m2, l2);
        }
        const float inv_l = 1.f / l;   // lanes 0..7 hold final stats for head = lane

        // pass 2: weighted aggregation
        for (int t = beg; t < end; ++t) {
            const int s = esrc[t];
            float aval = 0.f;
            if (lane < NH1) {
                float v = als1[s * NH1 + lane] + aldv;
                v = v > 0.f ? v : NEG_SLOPE * v;
                aval = __expf(v - m) * inv_l;
            }
            const float* xp = X + (size_t)s * IN_FEAT;
            float x0 = xp[lane];
            float x1 = xp[64 + lane];
            float x2 = xp[128 + lane];
            float x3 = (lane < 8) ? xp[192 + lane] : 0.f;
#pragma unroll
            for (int h = 0; h < NH1; ++h) {
                float a = __shfl(aval, h);
                acc[h][0] += a * x0;
                acc[h][1] += a * x1;
                acc[h][2] += a * x2;
                acc[h][3] += a * x3;
            }
        }
#pragma unroll
        for (int h = 0; h < NH1; ++h) {
            sb[wave][h * K1 + lane]        = f2bf(acc[h][0]);
            sb[wave][h * K1 + 64 + lane]   = f2bf(acc[h][1]);
            sb[wave][h * K1 + 128 + lane]  = f2bf(acc[h][2]);
            if (lane < 32) {
                unsigned short v3 = (lane < 8) ? f2bf(acc[h][3]) : (unsigned short)0;
                sb[wave][h * K1 + 192 + lane] = v3;
            }
        }
    } else {
        for (int j = lane; j < HSL; j += 64) sb[wave][j] = 0;
    }
    __syncthreads();

    // copy-out to fragment-major layout
    const int mtile = blockIdx.x >> 1;
    const int half8 = (blockIdx.x & 1) * 8;
    for (int q = threadIdx.x; q < 1792; q += 512) {
        const int i  = q & 7;          // node index within block
        const int kg = (q >> 3) & 3;
        const int r2 = q >> 5;         // [0,56)
        const int ks = r2 % 7;
        const int h  = r2 / 7;
        const uint4* s = (const uint4*)&sb[i][h * K1 + ks * 32 + kg * 8];
        uint4* d = (uint4*)(xaggb + (((size_t)mtile * NH1 + h) * 7 + ks) * 512
                                  + (size_t)(kg * 16 + half8 + i) * 8);
        *d = *s;
    }
}

// ---------- fused GEMM v17: fragment-major A+B, 4 heads per block, 2 partials ----------
// grid (M_PAD/32 = 314, NQ = 2); block 512.
// wave w: rg = w&1 (16-row mtile), cg = w>>1 (gemm1 cols cg*112, gemm2 cols cg*64).
__global__ __launch_bounds__(512, 2) void fused_gemm(const unsigned short* __restrict__ xaggb,
                                                     const unsigned short* __restrict__ W1f,
                                                     const float* __restrict__ b1,
                                                     const unsigned short* __restrict__ W2f,
                                                     float* __restrict__ h2p) {
    __shared__ unsigned short xhf[32 * XHS];   // 29184 B
    const int wave = threadIdx.x >> 6;
    const int lane = threadIdx.x & 63;
    const int row  = lane & 15;
    const int kg   = lane >> 4;
    const int rg   = wave & 1;
    const int cg   = wave >> 1;
    const int mtile = blockIdx.x * 2 + rg;
    const int m0    = mtile * 16;
    const int c0   = cg * 112;
    const int c2   = cg * 64;

    f32x4 oacc[4];
#pragma unroll
    for (int j = 0; j < 4; ++j) oacc[j] = (f32x4){0.f, 0.f, 0.f, 0.f};

#pragma unroll
    for (int hh = 0; hh < 4; ++hh) {
        const int h = blockIdx.y * 4 + hh;
        if (hh > 0) __syncthreads();   // previous head's gemm2 reads complete

        // ---- A fragments for head h (fragment-major: coalesced 1KB wave loads) ----
        const unsigned short* ap = xaggb + (((size_t)mtile * NH1 + h) * 7) * 512 + lane * 8;
        short8_t areg[7];
#pragma unroll
        for (int ks = 0; ks < 7; ++ks)
            areg[ks] = *(const short8_t*)(ap + ks * 512);

        // ---- gemm1: acc[j] = xagg_h[16 rows] @ W1_h[112 cols], K=224 ----
        const unsigned short* w1h = W1f + (((size_t)h * 28 + cg * 7) * 7) * 512 + lane * 8;
        f32x4 acc[7];
#pragma unroll
        for (int j = 0; j < 7; ++j) acc[j] = (f32x4){0.f, 0.f, 0.f, 0.f};
#pragma unroll
        for (int ks = 0; ks < 7; ++ks) {
            short8_t b[7];
#pragma unroll
            for (int j = 0; j < 7; ++j)
                b[j] = *(const short8_t*)(w1h + (size_t)(j * 7 + ks) * 512);
#pragma unroll
            for (int j = 0; j < 7; ++j)
                acc[j] = __builtin_amdgcn_mfma_f32_16x16x32_bf16(areg[ks], b[j], acc[j], 0, 0, 0);
        }

        // ---- bias + ELU -> xhf ----
#pragma unroll
        for (int j = 0; j < 7; ++j) {
            int cc = c0 + j * 16 + row;
            float bias = (cc < HID) ? b1[h * HID + cc] : 0.f;
#pragma unroll
            for (int r = 0; r < 4; ++r) {
                int rl = rg * 16 + kg * 4 + r;
                float v = acc[j][r] + bias;
                v = v > 0.f ? v : (__expf(v) - 1.f);
                xhf[rl * XHS + cc] = f2bf(v);
            }
        }
        __syncthreads();

        // ---- gemm2: oacc[j] += xh[16 rows x 416] @ W2_h[64 cols] ----
        const unsigned short* w2h = W2f + (((size_t)h * 16 + cg * 4) * 13) * 512 + lane * 8;
        const int rl = rg * 16 + row;
#pragma unroll
        for (int ks = 0; ks < 13; ++ks) {
            short8_t b[4];
#pragma unroll
            for (int j = 0; j < 4; ++j)
                b[j] = *(const short8_t*)(w2h + (size_t)(j * 13 + ks) * 512);
            short8_t a = *(const short8_t*)&xhf[rl * XHS + ks * 32 + kg * 8];
#pragma unroll
            for (int j = 0; j < 4; ++j)
                oacc[j] = __builtin_amdgcn_mfma_f32_16x16x32_bf16(a, b[j], oacc[j], 0, 0, 0);
        }
    }

    // ---- plain stores to per-quad partial buffer ----
    float* op = h2p + ((size_t)blockIdx.y * M_PAD + (m0 + kg * 4)) * OUT_FEAT;
#pragma unroll
    for (int j = 0; j < 4; ++j) {
        int cc = c2 + j * 16 + row;
        if (cc < OUT_FEAT) {
#pragma unroll
            for (int r = 0; r < 4; ++r)
                op[(size_t)r * OUT_FEAT + cc] = oacc[j][r];
        }
    }
}

// ---------- reduce 2 quad-partials -> h2, fused layer-2 logits ----------
__global__ __launch_bounds__(256) void reduce_att2(const float* __restrict__ h2p,
                                                   const float* __restrict__ a_src,
                                                   const float* __restrict__ a_dst,
                                                   float* __restrict__ h2,
                                                   float* __restrict__ als,
                                                   float* __restrict__ ald) {
    const int wave = threadIdx.x >> 6;
    const int lane = threadIdx.x & 63;
    const int row  = blockIdx.x * 4 + wave;

    f32x4 sum = {0.f, 0.f, 0.f, 0.f};
    if (lane < 50) {
        const float* p = h2p + (size_t)row * OUT_FEAT + lane * 4;
#pragma unroll
        for (int q = 0; q < NQ; ++q)
            sum += *(const f32x4*)(p + (size_t)q * M_PAD * OUT_FEAT);
        *(f32x4*)(h2 + (size_t)row * OUT_FEAT + lane * 4) = sum;
    }
    float ss = 0.f, sd = 0.f;
    if (lane < 50) {
        f32x4 as = *(const f32x4*)(a_src + lane * 4);
        f32x4 ad = *(const f32x4*)(a_dst + lane * 4);
#pragma unroll
        for (int j = 0; j < 4; ++j) { ss += sum[j] * as[j]; sd += sum[j] * ad[j]; }
    }
    for (int off = 32; off; off >>= 1) {
        ss += __shfl_down(ss, off);
        sd += __shfl_down(sd, off);
    }
    if (lane == 0 && row < N_NODES) { als[row] = ss; ald[row] = sd; }
}

// ---------- layer-2 aggregation, wave-parallel online softmax ----------
__global__ __launch_bounds__(256) void agg2_csr(const float* __restrict__ h2,
                                                const float* __restrict__ als2,
                                                const float* __restrict__ ald2,
                                                const int* __restrict__ offs,
                                                const int* __restrict__ esrc,
                                                const float* __restrict__ b2,
                                                float* __restrict__ out) {
    __shared__ float sm, sl;
    const int n = blockIdx.x;
    const int k = threadIdx.x;
    const float aldn = ald2[n];
    const int beg = offs[n], end = offs[n + 1];

    // pass 1: wave 0 strided + shfl merge
    if (k < 64) {
        float m = -INFINITY, l = 0.f;
        for (int t = beg + k; t < end; t += 64) {
            int s = esrc[t];
            float v = als2[s] + aldn;
            v = v > 0.f ? v : NEG_SLOPE * v;
            float mn = fmaxf(m, v);
            l = l * __expf(m - mn) + __expf(v - mn);
            m = mn;
        }
#pragma unroll
        for (int off = 1; off < 64; off <<= 1) {
            float m2 = __shfl_xor(m, off);
            float l2 = __shfl_xor(l, off);
            sm_merge(m, l, m2, l2);
        }
        if (k == 0) { sm = m; sl = 1.f / l; }
    }
    __syncthreads();
    const float m = sm, inv_l = sl;

    if (k >= OUT_FEAT) return;
    // pass 2: weighted gather
    float acc = 0.f;
    for (int t = beg; t < end; ++t) {
        int s = esrc[t];
        float v = als2[s] + aldn;
        v = v > 0.f ? v : NEG_SLOPE * v;
        float a = __expf(v - m) * inv_l;
        acc += a * h2[(size_t)s * OUT_FEAT + k];
    }
    out[(size_t)n * OUT_FEAT + k] = acc + b2[k];
}

// ---------- launch ----------
extern "C" void kernel_launch(void* const* d_in, const int* in_sizes, int n_in,
                              void* d_out, int out_size, void* d_ws, size_t ws_size,
                              hipStream_t stream) {
    const float* X   = (const float*)d_in[0];
    const int*   ei  = (const int*)d_in[1];
    const float* W1  = (const float*)d_in[2];
    const float* as1 = (const float*)d_in[3];
    const float* ad1 = (const float*)d_in[4];
    const float* b1  = (const float*)d_in[5];
    const float* W2  = (const float*)d_in[6];
    const float* as2 = (const float*)d_in[7];
    const float* ad2 = (const float*)d_in[8];
    const float* b2  = (const float*)d_in[9];
    float* out = (float*)d_out;

    char* base = (char*)d_ws;
    auto carve = [&](size_t bytes) -> void* {
        void* p = (void*)base;
        base += (bytes + 255) & ~(size_t)255;
        return p;
    };
    float* p_src1 = (float*)carve(NH1 * IN_FEAT * 4);
    float* p_dst1 = (float*)carve(NH1 * IN_FEAT * 4);
    float* als1   = (float*)carve(N_NODES * NH1 * 4);
    float* ald1   = (float*)carve(N_NODES * NH1 * 4);
    float* als2   = (float*)carve(N_NODES * 4);
    float* ald2   = (float*)carve(N_NODES * 4);
    float* h2     = (float*)carve((size_t)M_PAD * OUT_FEAT * 4);                  // 8.0 MB
    int* counts   = (int*)carve(N_NODES * 4);
    int* cursor   = (int*)carve(N_NODES * 4);
    int* offs     = (int*)carve((N_NODES + 1) * 4);
    int* esrc     = (int*)carve(ET * 4);
    unsigned short* xaggb = (unsigned short*)carve((size_t)(M_PAD / 16) * NH1 * 7 * 512 * 2); // 36 MB
    unsigned short* W1f   = (unsigned short*)carve((size_t)W1N * 2);              // 1.6 MB
    unsigned short* W2f   = (unsigned short*)carve((size_t)W2N * 2);              // 1.7 MB
    float* h2p    = (float*)carve((size_t)NQ * M_PAD * OUT_FEAT * 4);             // 16.1 MB

    // per-call init: only CSR counters (harness does not re-poison between replays)
    hipMemsetAsync(counts, 0, 2 * 40192, stream);  // counts + cursor (carve-aligned)

    // merged: prep_w + count + pvec
    pre_k<<<PW_BLK + CNT_BLK + PV_BLK, 256, 0, stream>>>(W1, W2, ei, as1, ad1,
                                                         W1f, W2f, counts, p_src1, p_dst1);
    scan_k<<<1, 1024, 0, stream>>>(counts, offs);
    // merged: scatter + att1x
    mid_k<<<SC_BLK + N_NODES, 512, 0, stream>>>(ei, offs, cursor, esrc,
                                                X, p_src1, p_dst1, als1, ald1);

    // Stage A: aggregated features (parallel online softmax), fragment-major output
    agg1x<<<M_PAD / 8, 512, 0, stream>>>(X, als1, ald1, offs, esrc, xaggb);

    // fused GEMM1 (+bias+ELU) + GEMM2; fragment-major A and B, 4 heads/block
    fused_gemm<<<dim3(M_PAD / 32, NQ), 512, 0, stream>>>(xaggb, W1f, b1, W2f, h2p);

    // reduce partials -> h2, fused layer-2 logits
    reduce_att2<<<M_PAD / 4, 256, 0, stream>>>(h2p, as2, ad2, h2, als2, ald2);

    // layer-2 aggregation (wave-parallel online softmax inside)
    agg2_csr<<<N_NODES, 256, 0, stream>>>(h2, als2, ald2, offs, esrc, b2, out);
}

// Round 24
// 218.391 us; speedup vs baseline: 1.0871x; 1.0871x over previous
//
#include <hip/hip_runtime.h>
#include <math.h>

#define N_NODES 10000
#define N_EDGES 80000
#define ET (N_EDGES + N_NODES)   // 90000 edges incl. self-loops
#define IN_FEAT 200
#define HID 400
#define NH1 8
#define F1 (NH1 * HID)           // 3200
#define OUT_FEAT 200
#define NEG_SLOPE 0.2f

#define M_PAD 10048              // 628 mtiles * 16
#define K1 224                   // per-head K pad (200 -> 224 = 7*32)
#define HSL (NH1 * K1)           // 1792 bf16 per node (LDS staging)
#define XH_K 416                 // per-head hidden K pad (400 -> 416 = 13*32)
#define C1P 448                  // gemm1 col pad (400 -> 448 = 28*16)
#define KALL (NH1 * XH_K)        // 3328
#define N2P2 256                 // gemm2 col pad
#define XHS 456                  // LDS xh row stride (ushorts)
#define NQ 4                     // head-pair partials

typedef __attribute__((ext_vector_type(8))) short short8_t;
typedef __attribute__((ext_vector_type(4))) float f32x4;

// ---------- helpers ----------

__device__ inline void edge_sd(const int* __restrict__ ei, int e, int& s, int& d) {
    if (e < N_EDGES) { s = ei[e]; d = ei[N_EDGES + e]; }
    else { s = e - N_EDGES; d = s; }
}

__device__ inline unsigned short f2bf(float x) {
    unsigned u = __float_as_uint(x);
    unsigned r = u + 0x7FFFu + ((u >> 16) & 1u);
    return (unsigned short)(r >> 16);
}

// NaN-safe online-softmax pair merge
__device__ inline void sm_merge(float& m, float& l, float m2, float l2) {
    float mn = fmaxf(m, m2);
    float t1 = (m  > -1e30f) ? l  * __expf(m  - mn) : 0.f;
    float t2 = (m2 > -1e30f) ? l2 * __expf(m2 - mn) : 0.f;
    m = mn; l = t1 + t2;
}

// ---------- merged pre-kernel: prep_w + count_k + pvec_k (independent work) ----------
#define W1N (NH1 * C1P * K1)     // 802816
#define W2N (N2P2 * KALL)        // 851968
#define PW_BLK ((W1N + W2N + 255) / 256)   // 6464
#define CNT_BLK ((ET + 255) / 256)         // 352
#define PV_BLK ((2 * NH1 * IN_FEAT + 255) / 256)  // 13
__global__ __launch_bounds__(256) void pre_k(const float* __restrict__ W1,
                                             const float* __restrict__ W2,
                                             const int* __restrict__ ei,
                                             const float* __restrict__ a_src,
                                             const float* __restrict__ a_dst,
                                             unsigned short* __restrict__ W1f,
                                             unsigned short* __restrict__ W2f,
                                             int* __restrict__ counts,
                                             float* __restrict__ p_src,
                                             float* __restrict__ p_dst) {
    const int bid = blockIdx.x;
    if (bid < PW_BLK) {
        int idx = bid * 256 + threadIdx.x;
        if (idx < W1N) {
            int e    = idx & 7;
            int lane = (idx >> 3) & 63;
            int rem  = idx >> 9;
            int ks   = rem % 7;
            int jgh  = rem / 7;
            int jg   = jgh % 28;
            int h    = jgh / 28;
            int c = jg * 16 + (lane & 15);
            int k = ks * 32 + (lane >> 4) * 8 + e;
            float v = (k < IN_FEAT && c < HID) ? W1[(size_t)k * F1 + h * HID + c] : 0.f;
            W1f[idx] = f2bf(v);
        } else if (idx < W1N + W2N) {
            int t    = idx - W1N;
            int e    = t & 7;
            int lane = (t >> 3) & 63;
            int rem  = t >> 9;
            int ks   = rem % 13;
            int cgh  = rem / 13;
            int cg   = cgh % 16;
            int h    = cgh / 16;
            int c = cg * 16 + (lane & 15);
            int k = ks * 32 + (lane >> 4) * 8 + e;
            float v = (c < OUT_FEAT && k < HID) ? W2[(size_t)(h * HID + k) * OUT_FEAT + c] : 0.f;
            W2f[t] = f2bf(v);
        }
    } else if (bid < PW_BLK + CNT_BLK) {
        int e = (bid - PW_BLK) * 256 + threadIdx.x;
        if (e < ET) {
            int s, d; edge_sd(ei, e, s, d);
            atomicAdd(&counts[d], 1);
        }
    } else {
        int idx = (bid - PW_BLK - CNT_BLK) * 256 + threadIdx.x;
        if (idx < 2 * NH1 * IN_FEAT) {
            int which = idx / (NH1 * IN_FEAT);
            int r = idx - which * (NH1 * IN_FEAT);
            int h = r / IN_FEAT, k = r - h * IN_FEAT;
            const float* av = (which == 0 ? a_src : a_dst) + h * HID;
            const float* wrow = W1 + (size_t)k * F1 + h * HID;
            float acc = 0.f;
            for (int c = 0; c < HID; ++c) acc += wrow[c] * av[c];
            (which == 0 ? p_src : p_dst)[h * IN_FEAT + k] = acc;
        }
    }
}

// ---------- scan ----------
__global__ __launch_bounds__(1024) void scan_k(const int* __restrict__ counts, int* __restrict__ offs) {
    __shared__ int part[1024];
    const int tid = threadIdx.x;
    const int base = tid * 10;
    int loc[10];
    int s = 0;
    for (int i = 0; i < 10; ++i) {
        int idx = base + i;
        int c = (idx < N_NODES) ? counts[idx] : 0;
        loc[i] = s; s += c;
    }
    part[tid] = s;
    __syncthreads();
    for (int off = 1; off < 1024; off <<= 1) {
        int v = (tid >= off) ? part[tid - off] : 0;
        __syncthreads();
        part[tid] += v;
        __syncthreads();
    }
    int pre = (tid > 0) ? part[tid - 1] : 0;
    for (int i = 0; i < 10; ++i) {
        int idx = base + i;
        if (idx < N_NODES) offs[idx] = pre + loc[i];
    }
    if (tid == 1023) offs[N_NODES] = part[1023];
}

// ---------- merged mid-kernel: scatter_k + att1x ----------
#define SC_BLK ((ET + 511) / 512)   // 176
__global__ __launch_bounds__(512) void mid_k(const int* __restrict__ ei,
                                             const int* __restrict__ offs,
                                             int* __restrict__ cursor,
                                             int* __restrict__ esrc,
                                             const float* __restrict__ X,
                                             const float* __restrict__ p_src,
                                             const float* __restrict__ p_dst,
                                             float* __restrict__ als,
                                             float* __restrict__ ald) {
    const int bid = blockIdx.x;
    if (bid < SC_BLK) {
        int e = bid * 512 + threadIdx.x;
        if (e < ET) {
            int s, d; edge_sd(ei, e, s, d);
            int pos = atomicAdd(&cursor[d], 1);
            esrc[offs[d] + pos] = s;
        }
    } else {
        const int n    = bid - SC_BLK;
        const int head = threadIdx.x >> 6;
        const int lane = threadIdx.x & 63;
        const float* xp = X + (size_t)n * IN_FEAT;
        const float* ps = p_src + head * IN_FEAT;
        const float* pd = p_dst + head * IN_FEAT;
        float ss = 0.f, sd = 0.f;
        for (int k = lane; k < IN_FEAT; k += 64) {
            float v = xp[k];
            ss += v * ps[k];
            sd += v * pd[k];
        }
        for (int off = 32; off; off >>= 1) {
            ss += __shfl_down(ss, off);
            sd += __shfl_down(sd, off);
        }
        if (lane == 0) { als[n * NH1 + head] = ss; ald[n * NH1 + head] = sd; }
    }
}

// ---------- Stage A: parallel online softmax + aggregation -> FRAGMENT-MAJOR xaggb ----------
// xaggb layout: ((mtile*8 + h)*7 + ks)*512 + (kg*16 + row)*8 + e
//   where node = mtile*16 + row, k = ks*32 + kg*8 + e
__global__ __launch_bounds__(512) void agg1x(const float* __restrict__ X,
                                             const float* __restrict__ als1,
                                             const float* __restrict__ ald1,
                                             const int* __restrict__ offs,
                                             const int* __restrict__ esrc,
                                             unsigned short* __restrict__ xaggb) {
    __shared__ unsigned short sb[8][HSL];   // 28672 B, [node][h*224 + k]
    const int wave = threadIdx.x >> 6;
    const int lane = threadIdx.x & 63;
    const int n = blockIdx.x * 8 + wave;

    if (n < N_NODES) {
        float acc[NH1][4];
#pragma unroll
        for (int h = 0; h < NH1; ++h)
#pragma unroll
            for (int g = 0; g < 4; ++g) acc[h][g] = 0.f;

        const int beg = offs[n], end = offs[n + 1];
        const int grp = lane >> 3;    // edge group 0..7
        const int hd  = lane & 7;     // head
        const float aldv = ald1[n * NH1 + hd];

        // pass 1: all 64 lanes — 8 edge-groups x 8 heads, shfl-merged
        float m = -INFINITY, l = 0.f;
        for (int t = beg + grp; t < end; t += 8) {
            const int s = esrc[t];
            float v = als1[s * NH1 + hd] + aldv;
            v = v > 0.f ? v : NEG_SLOPE * v;
            float mn = fmaxf(m, v);
            l = l * __expf(m - mn) + __expf(v - mn);
            m = mn;
        }
#pragma unroll
        for (int off = 8; off < 64; off <<= 1) {
            float m2 = __shfl_xor(m, off);
            float l2 = __shfl_xor(l, off);
            sm_merge(m, l, m2, l2);
        }
        const float inv_l = 1.f / l;   // lanes 0..7 hold final stats for head = lane

        // pass 2: weighted aggregation
        for (int t = beg; t < end; ++t) {
            const int s = esrc[t];
            float aval = 0.f;
            if (lane < NH1) {
                float v = als1[s * NH1 + lane] + aldv;
                v = v > 0.f ? v : NEG_SLOPE * v;
                aval = __expf(v - m) * inv_l;
            }
            const float* xp = X + (size_t)s * IN_FEAT;
            float x0 = xp[lane];
            float x1 = xp[64 + lane];
            float x2 = xp[128 + lane];
            float x3 = (lane < 8) ? xp[192 + lane] : 0.f;
#pragma unroll
            for (int h = 0; h < NH1; ++h) {
                float a = __shfl(aval, h);
                acc[h][0] += a * x0;
                acc[h][1] += a * x1;
                acc[h][2] += a * x2;
                acc[h][3] += a * x3;
            }
        }
#pragma unroll
        for (int h = 0; h < NH1; ++h) {
            sb[wave][h * K1 + lane]        = f2bf(acc[h][0]);
            sb[wave][h * K1 + 64 + lane]   = f2bf(acc[h][1]);
            sb[wave][h * K1 + 128 + lane]  = f2bf(acc[h][2]);
            if (lane < 32) {
                unsigned short v3 = (lane < 8) ? f2bf(acc[h][3]) : (unsigned short)0;
                sb[wave][h * K1 + 192 + lane] = v3;
            }
        }
    } else {
        for (int j = lane; j < HSL; j += 64) sb[wave][j] = 0;
    }
    __syncthreads();

    // copy-out to fragment-major layout
    const int mtile = blockIdx.x >> 1;
    const int half8 = (blockIdx.x & 1) * 8;
    for (int q = threadIdx.x; q < 1792; q += 512) {
        const int i  = q & 7;          // node index within block
        const int kg = (q >> 3) & 3;
        const int r2 = q >> 5;         // [0,56)
        const int ks = r2 % 7;
        const int h  = r2 / 7;
        const uint4* s = (const uint4*)&sb[i][h * K1 + ks * 32 + kg * 8];
        uint4* d = (uint4*)(xaggb + (((size_t)mtile * NH1 + h) * 7 + ks) * 512
                                  + (size_t)(kg * 16 + half8 + i) * 8);
        *d = *s;
    }
}

// ---------- fused GEMM v16: fragment-major A AND B (all loads coalesced) ----------
// grid (M_PAD/32 = 314, NQ = 4); block 512.
// wave w: rg = w&1 (16-row mtile), cg = w>>1 (gemm1 cols cg*112, gemm2 cols cg*64).
__global__ __launch_bounds__(512, 2) void fused_gemm(const unsigned short* __restrict__ xaggb,
                                                     const unsigned short* __restrict__ W1f,
                                                     const float* __restrict__ b1,
                                                     const unsigned short* __restrict__ W2f,
                                                     float* __restrict__ h2p) {
    __shared__ unsigned short xhf[32 * XHS];   // 29184 B
    const int wave = threadIdx.x >> 6;
    const int lane = threadIdx.x & 63;
    const int row  = lane & 15;
    const int kg   = lane >> 4;
    const int rg   = wave & 1;
    const int cg   = wave >> 1;
    const int mtile = blockIdx.x * 2 + rg;
    const int m0    = mtile * 16;
    const int c0   = cg * 112;
    const int c2   = cg * 64;

    f32x4 oacc[4];
#pragma unroll
    for (int j = 0; j < 4; ++j) oacc[j] = (f32x4){0.f, 0.f, 0.f, 0.f};

#pragma unroll
    for (int hh = 0; hh < 2; ++hh) {
        const int h = blockIdx.y * 2 + hh;
        if (hh > 0) __syncthreads();   // previous head's gemm2 reads complete

        // ---- A fragments for head h (fragment-major: coalesced 1KB wave loads) ----
        const unsigned short* ap = xaggb + (((size_t)mtile * NH1 + h) * 7) * 512 + lane * 8;
        short8_t areg[7];
#pragma unroll
        for (int ks = 0; ks < 7; ++ks)
            areg[ks] = *(const short8_t*)(ap + ks * 512);

        // ---- gemm1: acc[j] = xagg_h[16 rows] @ W1_h[112 cols], K=224 ----
        const unsigned short* w1h = W1f + (((size_t)h * 28 + cg * 7) * 7) * 512 + lane * 8;
        f32x4 acc[7];
#pragma unroll
        for (int j = 0; j < 7; ++j) acc[j] = (f32x4){0.f, 0.f, 0.f, 0.f};
#pragma unroll
        for (int ks = 0; ks < 7; ++ks) {
            short8_t b[7];
#pragma unroll
            for (int j = 0; j < 7; ++j)
                b[j] = *(const short8_t*)(w1h + (size_t)(j * 7 + ks) * 512);
#pragma unroll
            for (int j = 0; j < 7; ++j)
                acc[j] = __builtin_amdgcn_mfma_f32_16x16x32_bf16(areg[ks], b[j], acc[j], 0, 0, 0);
        }

        // ---- bias + ELU -> xhf ----
#pragma unroll
        for (int j = 0; j < 7; ++j) {
            int cc = c0 + j * 16 + row;
            float bias = (cc < HID) ? b1[h * HID + cc] : 0.f;
#pragma unroll
            for (int r = 0; r < 4; ++r) {
                int rl = rg * 16 + kg * 4 + r;
                float v = acc[j][r] + bias;
                v = v > 0.f ? v : (__expf(v) - 1.f);
                xhf[rl * XHS + cc] = f2bf(v);
            }
        }
        __syncthreads();

        // ---- gemm2: oacc[j] += xh[16 rows x 416] @ W2_h[64 cols] ----
        const unsigned short* w2h = W2f + (((size_t)h * 16 + cg * 4) * 13) * 512 + lane * 8;
        const int rl = rg * 16 + row;
#pragma unroll
        for (int ks = 0; ks < 13; ++ks) {
            short8_t b[4];
#pragma unroll
            for (int j = 0; j < 4; ++j)
                b[j] = *(const short8_t*)(w2h + (size_t)(j * 13 + ks) * 512);
            short8_t a = *(const short8_t*)&xhf[rl * XHS + ks * 32 + kg * 8];
#pragma unroll
            for (int j = 0; j < 4; ++j)
                oacc[j] = __builtin_amdgcn_mfma_f32_16x16x32_bf16(a, b[j], oacc[j], 0, 0, 0);
        }
    }

    // ---- plain stores to per-pair partial buffer ----
    float* op = h2p + ((size_t)blockIdx.y * M_PAD + (m0 + kg * 4)) * OUT_FEAT;
#pragma unroll
    for (int j = 0; j < 4; ++j) {
        int cc = c2 + j * 16 + row;
        if (cc < OUT_FEAT) {
#pragma unroll
            for (int r = 0; r < 4; ++r)
                op[(size_t)r * OUT_FEAT + cc] = oacc[j][r];
        }
    }
}

// ---------- reduce 4 pair-partials -> h2, fused layer-2 logits ----------
__global__ __launch_bounds__(256) void reduce_att2(const float* __restrict__ h2p,
                                                   const float* __restrict__ a_src,
                                                   const float* __restrict__ a_dst,
                                                   float* __restrict__ h2,
                                                   float* __restrict__ als,
                                                   float* __restrict__ ald) {
    const int wave = threadIdx.x >> 6;
    const int lane = threadIdx.x & 63;
    const int row  = blockIdx.x * 4 + wave;

    f32x4 sum = {0.f, 0.f, 0.f, 0.f};
    if (lane < 50) {
        const float* p = h2p + (size_t)row * OUT_FEAT + lane * 4;
#pragma unroll
        for (int q = 0; q < NQ; ++q)
            sum += *(const f32x4*)(p + (size_t)q * M_PAD * OUT_FEAT);
        *(f32x4*)(h2 + (size_t)row * OUT_FEAT + lane * 4) = sum;
    }
    float ss = 0.f, sd = 0.f;
    if (lane < 50) {
        f32x4 as = *(const f32x4*)(a_src + lane * 4);
        f32x4 ad = *(const f32x4*)(a_dst + lane * 4);
#pragma unroll
        for (int j = 0; j < 4; ++j) { ss += sum[j] * as[j]; sd += sum[j] * ad[j]; }
    }
    for (int off = 32; off; off >>= 1) {
        ss += __shfl_down(ss, off);
        sd += __shfl_down(sd, off);
    }
    if (lane == 0 && row < N_NODES) { als[row] = ss; ald[row] = sd; }
}

// ---------- layer-2 aggregation, wave-parallel online softmax ----------
__global__ __launch_bounds__(256) void agg2_csr(const float* __restrict__ h2,
                                                const float* __restrict__ als2,
                                                const float* __restrict__ ald2,
                                                const int* __restrict__ offs,
                                                const int* __restrict__ esrc,
                                                const float* __restrict__ b2,
                                                float* __restrict__ out) {
    __shared__ float sm, sl;
    const int n = blockIdx.x;
    const int k = threadIdx.x;
    const float aldn = ald2[n];
    const int beg = offs[n], end = offs[n + 1];

    // pass 1: wave 0 strided + shfl merge
    if (k < 64) {
        float m = -INFINITY, l = 0.f;
        for (int t = beg + k; t < end; t += 64) {
            int s = esrc[t];
            float v = als2[s] + aldn;
            v = v > 0.f ? v : NEG_SLOPE * v;
            float mn = fmaxf(m, v);
            l = l * __expf(m - mn) + __expf(v - mn);
            m = mn;
        }
#pragma unroll
        for (int off = 1; off < 64; off <<= 1) {
            float m2 = __shfl_xor(m, off);
            float l2 = __shfl_xor(l, off);
            sm_merge(m, l, m2, l2);
        }
        if (k == 0) { sm = m; sl = 1.f / l; }
    }
    __syncthreads();
    const float m = sm, inv_l = sl;

    if (k >= OUT_FEAT) return;
    // pass 2: weighted gather
    float acc = 0.f;
    for (int t = beg; t < end; ++t) {
        int s = esrc[t];
        float v = als2[s] + aldn;
        v = v > 0.f ? v : NEG_SLOPE * v;
        float a = __expf(v - m) * inv_l;
        acc += a * h2[(size_t)s * OUT_FEAT + k];
    }
    out[(size_t)n * OUT_FEAT + k] = acc + b2[k];
}

// ---------- launch ----------
extern "C" void kernel_launch(void* const* d_in, const int* in_sizes, int n_in,
                              void* d_out, int out_size, void* d_ws, size_t ws_size,
                              hipStream_t stream) {
    const float* X   = (const float*)d_in[0];
    const int*   ei  = (const int*)d_in[1];
    const float* W1  = (const float*)d_in[2];
    const float* as1 = (const float*)d_in[3];
    const float* ad1 = (const float*)d_in[4];
    const float* b1  = (const float*)d_in[5];
    const float* W2  = (const float*)d_in[6];
    const float* as2 = (const float*)d_in[7];
    const float* ad2 = (const float*)d_in[8];
    const float* b2  = (const float*)d_in[9];
    float* out = (float*)d_out;

    char* base = (char*)d_ws;
    auto carve = [&](size_t bytes) -> void* {
        void* p = (void*)base;
        base += (bytes + 255) & ~(size_t)255;
        return p;
    };
    float* p_src1 = (float*)carve(NH1 * IN_FEAT * 4);
    float* p_dst1 = (float*)carve(NH1 * IN_FEAT * 4);
    float* als1   = (float*)carve(N_NODES * NH1 * 4);
    float* ald1   = (float*)carve(N_NODES * NH1 * 4);
    float* als2   = (float*)carve(N_NODES * 4);
    float* ald2   = (float*)carve(N_NODES * 4);
    float* h2     = (float*)carve((size_t)M_PAD * OUT_FEAT * 4);                  // 8.0 MB
    int* counts   = (int*)carve(N_NODES * 4);
    int* cursor   = (int*)carve(N_NODES * 4);
    int* offs     = (int*)carve((N_NODES + 1) * 4);
    int* esrc     = (int*)carve(ET * 4);
    unsigned short* xaggb = (unsigned short*)carve((size_t)(M_PAD / 16) * NH1 * 7 * 512 * 2); // 36 MB
    unsigned short* W1f   = (unsigned short*)carve((size_t)W1N * 2);              // 1.6 MB
    unsigned short* W2f   = (unsigned short*)carve((size_t)W2N * 2);              // 1.7 MB
    float* h2p    = (float*)carve((size_t)NQ * M_PAD * OUT_FEAT * 4);             // 32.2 MB

    // per-call init: only CSR counters (harness does not re-poison between replays)
    hipMemsetAsync(counts, 0, 2 * 40192, stream);  // counts + cursor (carve-aligned)

    // merged: prep_w + count + pvec
    pre_k<<<PW_BLK + CNT_BLK + PV_BLK, 256, 0, stream>>>(W1, W2, ei, as1, ad1,
                                                         W1f, W2f, counts, p_src1, p_dst1);
    scan_k<<<1, 1024, 0, stream>>>(counts, offs);
    // merged: scatter + att1x
    mid_k<<<SC_BLK + N_NODES, 512, 0, stream>>>(ei, offs, cursor, esrc,
                                                X, p_src1, p_dst1, als1, ald1);

    // Stage A: aggregated features (parallel online softmax), fragment-major output
    agg1x<<<M_PAD / 8, 512, 0, stream>>>(X, als1, ald1, offs, esrc, xaggb);

    // fused GEMM1 (+bias+ELU) + GEMM2; fragment-major A and B
    fused_gemm<<<dim3(M_PAD / 32, NQ), 512, 0, stream>>>(xaggb, W1f, b1, W2f, h2p);

    // reduce partials -> h2, fused layer-2 logits
    reduce_att2<<<M_PAD / 4, 256, 0, stream>>>(h2p, as2, ad2, h2, als2, ald2);

    // layer-2 aggregation (wave-parallel online softmax inside)
    agg2_csr<<<N_NODES, 256, 0, stream>>>(h2, als2, ald2, offs, esrc, b2, out);
}